// Round 2
// baseline (1288.173 us; speedup 1.0000x reference)
//
#include <hip/hip_runtime.h>

// BlockSparseLinear: out[M,N] = 2 * (x[M,K] @ (W .* mask)^T) + bias[N]
// M = 16384, N = 4096, K = 4096, mask 32x32 blocks over (N/32, K/32) = (128,128).
// Fast path: pre-convert x and masked W to bf16 in d_ws, PRE-SWIZZLED
// (16B-chunk c -> c ^ (row&7) within each 128B span) so global_load_lds's
// linear LDS dest produces a bank-conflict-free image; ds_read_b128 applies
// the same XOR. m97 GEMM structure: 128x128 tile, BK=64, 4 waves, 16x16x32
// MFMA, 2 barriers/K-step. Wave-uniform mask tests skip zero-block B loads
// (25%) and zero-block MFMA clusters (~50%).

typedef short s16x8 __attribute__((ext_vector_type(8)));
typedef float f32x4 __attribute__((ext_vector_type(4)));
typedef unsigned short u16;

#define M_TOT 16384
#define N_TOT 4096
#define K_TOT 4096
#define MASK_DIM 128
#define LDS_STRIDE 72  // legacy fallback kernel only

__device__ __forceinline__ u16 f2bf(float f) {
  union { float f; unsigned u; } v; v.f = f;
  unsigned r = v.u + 0x7FFFu + ((v.u >> 16) & 1u);  // round-to-nearest-even
  return (u16)(r >> 16);
}

__device__ __forceinline__ void load16_to_lds(const u16* g, u16* l) {
  __builtin_amdgcn_global_load_lds(
      (const __attribute__((address_space(1))) void*)g,
      (__attribute__((address_space(3))) void*)l, 16, 0, 0);
}

// ---------------------------------------------------------------------------
// Mask normalization (format auto-detect: byte-bool vs int32/float words).
// ---------------------------------------------------------------------------
__global__ void prep_mask_kernel(const unsigned char* __restrict__ m,
                                 unsigned char* __restrict__ outm) {
  __shared__ int s_ok[4];
  const int t = threadIdx.x;
  unsigned v = reinterpret_cast<const unsigned*>(m)[t];
  bool wordlike = (v <= 1u) || (v == 0x3F800000u);
  unsigned long long b = __ballot(wordlike);
  if ((t & 63) == 0) s_ok[t >> 6] = (b == ~0ull) ? 1 : 0;
  __syncthreads();
  const bool word_fmt = s_ok[0] && s_ok[1] && s_ok[2] && s_ok[3];
  for (int i = t; i < MASK_DIM * MASK_DIM; i += 256) {
    bool nz = word_fmt ? (reinterpret_cast<const unsigned*>(m)[i] != 0u)
                       : (m[i] != 0);
    outm[i] = nz ? 1 : 0;
  }
}

// ---------------------------------------------------------------------------
// x fp32 [M][K] -> bf16, pre-swizzled: elem (row,k) stored at byte
//   row*2K + (k>>6)*128 + ((((k>>3)&7) ^ (row&7))*16) + (k&7)*2
// ---------------------------------------------------------------------------
__global__ void prep_x_swz_kernel(const float* __restrict__ x,
                                  u16* __restrict__ xb) {
  const size_t t = (size_t)blockIdx.x * 256 + threadIdx.x;  // 16B-chunk index
  const size_t row = t >> 9;        // 512 chunks per 4096-elem row
  const int wc = (int)(t & 511);
  const int blk = wc >> 3;
  const int c = wc & 7;
  const float4 v0 = *reinterpret_cast<const float4*>(x + row * K_TOT + wc * 8);
  const float4 v1 = *reinterpret_cast<const float4*>(x + row * K_TOT + wc * 8 + 4);
  s16x8 b;
  b[0] = (short)f2bf(v0.x); b[1] = (short)f2bf(v0.y);
  b[2] = (short)f2bf(v0.z); b[3] = (short)f2bf(v0.w);
  b[4] = (short)f2bf(v1.x); b[5] = (short)f2bf(v1.y);
  b[6] = (short)f2bf(v1.z); b[7] = (short)f2bf(v1.w);
  *reinterpret_cast<s16x8*>(xb + row * K_TOT + blk * 64 +
                            (size_t)((c ^ ((int)row & 7)) * 8)) = b;
}

// ---------------------------------------------------------------------------
// W fp32 [N][K] -> masked bf16, pre-swizzled (same scheme).
// ---------------------------------------------------------------------------
__global__ void prep_w_swz_kernel(const float* __restrict__ w,
                                  const unsigned char* __restrict__ mask8,
                                  u16* __restrict__ wb) {
  const size_t t = (size_t)blockIdx.x * 256 + threadIdx.x;
  const size_t row = t >> 9;
  const int wc = (int)(t & 511);
  const int blk = wc >> 3;
  const int c = wc & 7;
  s16x8 b = {};
  if (mask8[((int)row >> 5) * MASK_DIM + (wc >> 2)]) {
    const float4 v0 = *reinterpret_cast<const float4*>(w + row * K_TOT + wc * 8);
    const float4 v1 = *reinterpret_cast<const float4*>(w + row * K_TOT + wc * 8 + 4);
    b[0] = (short)f2bf(v0.x); b[1] = (short)f2bf(v0.y);
    b[2] = (short)f2bf(v0.z); b[3] = (short)f2bf(v0.w);
    b[4] = (short)f2bf(v1.x); b[5] = (short)f2bf(v1.y);
    b[6] = (short)f2bf(v1.z); b[7] = (short)f2bf(v1.w);
  }
  *reinterpret_cast<s16x8*>(wb + row * K_TOT + blk * 64 +
                            (size_t)((c ^ ((int)row & 7)) * 8)) = b;
}

// ---------------------------------------------------------------------------
// Legacy linear prep_w (for the ws-fits-W-only fallback path).
// ---------------------------------------------------------------------------
__global__ void prep_w_kernel(const float* __restrict__ w,
                              const unsigned char* __restrict__ mask8,
                              u16* __restrict__ wb) {
  const size_t e = ((size_t)blockIdx.x * blockDim.x + threadIdx.x) * 4;
  const int n = (int)(e >> 12);
  const int k = (int)(e & 4095);
  const float4 v = *reinterpret_cast<const float4*>(w + e);
  ushort4 bvec;
  if (mask8[(n >> 5) * MASK_DIM + (k >> 5)]) {
    bvec.x = f2bf(v.x); bvec.y = f2bf(v.y); bvec.z = f2bf(v.z); bvec.w = f2bf(v.w);
  } else {
    bvec.x = 0; bvec.y = 0; bvec.z = 0; bvec.w = 0;
  }
  *reinterpret_cast<ushort4*>(wb + e) = bvec;
}

// ---------------------------------------------------------------------------
// Fast GEMM: C = 2 * A @ B^T + bias, A=xb, B=wb (both bf16 pre-swizzled).
// 128x128 tile, BK=64, 4 waves (2x2), global_load_lds staging, mask skips.
// ---------------------------------------------------------------------------
__global__ __launch_bounds__(256) void gemm_fast_kernel(
    const u16* __restrict__ xb, const u16* __restrict__ wb,
    const unsigned char* __restrict__ mask8,
    const float* __restrict__ bias, float* __restrict__ out) {
  __shared__ __align__(16) u16 As[128 * 64];
  __shared__ __align__(16) u16 Bs[128 * 64];

  const int tid = threadIdx.x;
  const int lane = tid & 63;
  const int wave = tid >> 6;
  const int wr = wave >> 1;
  const int wcn = wave & 1;

  // XCD-aware bijective swizzle (grid = 4096, divisible by 8).
  int id = blockIdx.x;
  const int cpx = gridDim.x >> 3;
  id = (id & 7) * cpx + (id >> 3);
  const int bm = (id >> 5) << 7;
  const int bn = (id & 31) << 7;

  const int srow = lane >> 3;   // staging: row within 8-row seg
  const int schk = lane & 7;    // staging: 16B chunk
  const int lrow = lane & 15;
  const int g = lane >> 4;
  const int sw = (lrow & 7) << 4;  // read-side XOR (tile rows: ra&7 == lrow&7)

  const int mrow0 = (bn + wcn * 64) >> 5;  // mask row for frags n=0,1
  const int mrow1 = mrow0 + 1;             // mask row for frags n=2,3

  f32x4 acc[4][4] = {};

  for (int k0 = 0; k0 < K_TOT; k0 += 64) {
    const int kb = k0 >> 5;
#pragma unroll
    for (int i = 0; i < 4; ++i) {
      const int seg = wave * 4 + i;
      load16_to_lds(xb + (size_t)(bm + seg * 8 + srow) * K_TOT + k0 + schk * 8,
                    As + seg * 512);
      const int mr = (bn + seg * 8) >> 5;
      if (mask8[mr * MASK_DIM + kb] | mask8[mr * MASK_DIM + kb + 1]) {
        load16_to_lds(wb + (size_t)(bn + seg * 8 + srow) * K_TOT + k0 + schk * 8,
                      Bs + seg * 512);
      }
    }
    __syncthreads();

#pragma unroll
    for (int ks = 0; ks < 2; ++ks) {
      const int m0v = mask8[mrow0 * MASK_DIM + kb + ks];
      const int m1v = mask8[mrow1 * MASK_DIM + kb + ks];
      if (!(m0v | m1v)) continue;
      const int kofs = ks * 64;
      s16x8 af[4];
#pragma unroll
      for (int m = 0; m < 4; ++m) {
        const int ra = wr * 64 + m * 16 + lrow;
        af[m] = *reinterpret_cast<const s16x8*>(
            (const char*)As + ra * 128 + ((kofs + g * 16) ^ sw));
      }
      if (m0v) {
#pragma unroll
        for (int n = 0; n < 2; ++n) {
          const int rb = wcn * 64 + n * 16 + lrow;
          const s16x8 bf = *reinterpret_cast<const s16x8*>(
              (const char*)Bs + rb * 128 + ((kofs + g * 16) ^ sw));
#pragma unroll
          for (int m = 0; m < 4; ++m)
            acc[m][n] = __builtin_amdgcn_mfma_f32_16x16x32_bf16(af[m], bf,
                                                                acc[m][n], 0, 0, 0);
        }
      }
      if (m1v) {
#pragma unroll
        for (int n = 2; n < 4; ++n) {
          const int rb = wcn * 64 + n * 16 + lrow;
          const s16x8 bf = *reinterpret_cast<const s16x8*>(
              (const char*)Bs + rb * 128 + ((kofs + g * 16) ^ sw));
#pragma unroll
          for (int m = 0; m < 4; ++m)
            acc[m][n] = __builtin_amdgcn_mfma_f32_16x16x32_bf16(af[m], bf,
                                                                acc[m][n], 0, 0, 0);
        }
      }
    }
    __syncthreads();
  }

  // epilogue: out = 2*acc + bias. C/D frag: col = lane&15, row = (lane>>4)*4+j
#pragma unroll
  for (int n = 0; n < 4; ++n) {
    const int gcol = bn + wcn * 64 + n * 16 + lrow;
    const float bv = bias[gcol];
#pragma unroll
    for (int m = 0; m < 4; ++m) {
      const int grow = bm + wr * 64 + m * 16 + (g << 2);
#pragma unroll
      for (int j = 0; j < 4; ++j) {
        out[(size_t)(grow + j) * N_TOT + gcol] = 2.0f * acc[m][n][j] + bv;
      }
    }
  }
}

// ---------------------------------------------------------------------------
// Legacy reg-staged GEMM (fallback when ws can't hold xb).
// ---------------------------------------------------------------------------
template <bool PREPPED>
__global__ __launch_bounds__(256) void gemm_kernel(
    const float* __restrict__ x, const u16* __restrict__ wb,
    const float* __restrict__ wf, const unsigned char* __restrict__ mask8,
    const float* __restrict__ bias, float* __restrict__ out) {
  __shared__ __align__(16) u16 As[128 * LDS_STRIDE];
  __shared__ __align__(16) u16 Bs[128 * LDS_STRIDE];

  const int tid = threadIdx.x;
  const int lane = tid & 63;
  const int wave = tid >> 6;
  const int wr = wave >> 1;
  const int wcn = wave & 1;

  int id = blockIdx.x;
  const int cpx = gridDim.x >> 3;
  id = (id & 7) * cpx + (id >> 3);
  const int bm = (id >> 5) << 7;
  const int bn = (id & 31) << 7;

  const int arow = tid >> 4;
  const int acol = (tid & 15) << 2;
  const int brow = tid >> 3;
  const int bcol = (tid & 7) << 3;

  const int lrow = lane & 15;
  const int lgo = (lane >> 4) << 3;

  f32x4 acc[4][4] = {};

  for (int k0 = 0; k0 < K_TOT; k0 += 64) {
#pragma unroll
    for (int r = 0; r < 8; ++r) {
      const int row = arow + r * 16;
      const float4 v = *reinterpret_cast<const float4*>(
          x + (size_t)(bm + row) * K_TOT + k0 + acol);
      ushort4 bvec;
      bvec.x = f2bf(v.x); bvec.y = f2bf(v.y); bvec.z = f2bf(v.z); bvec.w = f2bf(v.w);
      *reinterpret_cast<ushort4*>(&As[row * LDS_STRIDE + acol]) = bvec;
    }
    if (PREPPED) {
#pragma unroll
      for (int r = 0; r < 4; ++r) {
        const int row = brow + r * 32;
        const s16x8 v = *reinterpret_cast<const s16x8*>(
            wb + (size_t)(bn + row) * K_TOT + k0 + bcol);
        *reinterpret_cast<s16x8*>(&Bs[row * LDS_STRIDE + bcol]) = v;
      }
    } else {
#pragma unroll
      for (int r = 0; r < 8; ++r) {
        const int row = arow + r * 16;
        const float4 v = *reinterpret_cast<const float4*>(
            wf + (size_t)(bn + row) * K_TOT + k0 + acol);
        ushort4 bvec;
        bvec.x = 0; bvec.y = 0; bvec.z = 0; bvec.w = 0;
        if (mask8[((bn + row) >> 5) * MASK_DIM + ((k0 + acol) >> 5)]) {
          bvec.x = f2bf(v.x); bvec.y = f2bf(v.y); bvec.z = f2bf(v.z); bvec.w = f2bf(v.w);
        }
        *reinterpret_cast<ushort4*>(&Bs[row * LDS_STRIDE + acol]) = bvec;
      }
    }
    __syncthreads();

#pragma unroll
    for (int ks = 0; ks < 2; ++ks) {
      s16x8 af[4], bfv[4];
#pragma unroll
      for (int m = 0; m < 4; ++m)
        af[m] = *reinterpret_cast<const s16x8*>(
            &As[(wr * 64 + m * 16 + lrow) * LDS_STRIDE + ks * 32 + lgo]);
#pragma unroll
      for (int n = 0; n < 4; ++n)
        bfv[n] = *reinterpret_cast<const s16x8*>(
            &Bs[(wcn * 64 + n * 16 + lrow) * LDS_STRIDE + ks * 32 + lgo]);
#pragma unroll
      for (int m = 0; m < 4; ++m)
#pragma unroll
        for (int n = 0; n < 4; ++n)
          acc[m][n] = __builtin_amdgcn_mfma_f32_16x16x32_bf16(af[m], bfv[n],
                                                              acc[m][n], 0, 0, 0);
    }
    __syncthreads();
  }

#pragma unroll
  for (int n = 0; n < 4; ++n) {
    const int gcol = bn + wcn * 64 + n * 16 + lrow;
    const float bv = bias[gcol];
#pragma unroll
    for (int m = 0; m < 4; ++m) {
      const int grow = bm + wr * 64 + m * 16 + ((lane >> 4) << 2);
#pragma unroll
      for (int j = 0; j < 4; ++j) {
        out[(size_t)(grow + j) * N_TOT + gcol] = 2.0f * acc[m][n][j] + bv;
      }
    }
  }
}

extern "C" void kernel_launch(void* const* d_in, const int* in_sizes, int n_in,
                              void* d_out, int out_size, void* d_ws, size_t ws_size,
                              hipStream_t stream) {
  const float* x = (const float*)d_in[0];
  const float* w = (const float*)d_in[1];
  const float* bias = (const float*)d_in[2];
  const unsigned char* mask_raw = (const unsigned char*)d_in[3];
  float* out = (float*)d_out;

  unsigned char* ws_mask = (unsigned char*)d_ws;            // 16 KiB (64 KiB slot)
  u16* wb = (u16*)((char*)d_ws + 65536);                    // 32 MiB bf16 W
  u16* xb = (u16*)((char*)d_ws + 65536 +
                   (size_t)N_TOT * K_TOT * sizeof(u16));    // 128 MiB bf16 x
  const size_t need_w = 65536 + (size_t)N_TOT * K_TOT * sizeof(u16);
  const size_t need_full = need_w + (size_t)M_TOT * K_TOT * sizeof(u16);

  prep_mask_kernel<<<1, 256, 0, stream>>>(mask_raw, ws_mask);

  if (ws_size >= need_full) {
    prep_w_swz_kernel<<<(N_TOT * (K_TOT / 8)) / 256, 256, 0, stream>>>(w, ws_mask, wb);
    prep_x_swz_kernel<<<(M_TOT * (K_TOT / 8)) / 256, 256, 0, stream>>>(x, xb);
    gemm_fast_kernel<<<(M_TOT / 128) * (N_TOT / 128), 256, 0, stream>>>(
        xb, wb, ws_mask, bias, out);
  } else if (ws_size >= need_w) {
    prep_w_kernel<<<(N_TOT * K_TOT) / (256 * 4), 256, 0, stream>>>(w, ws_mask, wb);
    gemm_kernel<true><<<(M_TOT / 128) * (N_TOT / 128), 256, 0, stream>>>(
        x, wb, nullptr, nullptr, bias, out);
  } else {
    gemm_kernel<false><<<(M_TOT / 128) * (N_TOT / 128), 256, 0, stream>>>(
        x, nullptr, w, ws_mask, bias, out);
  }
}

// Round 3
// 686.970 us; speedup vs baseline: 1.8752x; 1.8752x over previous
//
#include <hip/hip_runtime.h>

// BlockSparseLinear: out[M,N] = 2 * (x[M,K] @ (W .* mask)^T) + bias[N]
// M = 16384, N = 4096, K = 4096, mask 32x32 blocks over (128,128).
// Fast path: prep x and masked W to bf16 in d_ws, PRE-SWIZZLED (16B chunk
// c -> c ^ (row&7) within each 128B span); GEMM is the 8-phase 256x256
// template: BK=64, 8 waves (2Mx4N), 128KB LDS double-buffer, stage-early +
// single vmcnt(0) drain per K-tile (~3 phases of slack), per-phase
// barrier/lgkmcnt(0)/setprio(1) MFMA clusters, XCD-aware block swizzle.

typedef short s16x8 __attribute__((ext_vector_type(8)));
typedef float f32x4 __attribute__((ext_vector_type(4)));
typedef unsigned short u16;

#define M_TOT 16384
#define N_TOT 4096
#define K_TOT 4096
#define MASK_DIM 128
#define LDS_STRIDE 72  // legacy fallback kernel only

__device__ __forceinline__ u16 f2bf(float f) {
  union { float f; unsigned u; } v; v.f = f;
  unsigned r = v.u + 0x7FFFu + ((v.u >> 16) & 1u);  // round-to-nearest-even
  return (u16)(r >> 16);
}

__device__ __forceinline__ void load16_to_lds(const u16* g, u16* l) {
  __builtin_amdgcn_global_load_lds(
      (const __attribute__((address_space(1))) void*)g,
      (__attribute__((address_space(3))) void*)l, 16, 0, 0);
}

// ---------------------------------------------------------------------------
// Mask normalization (format auto-detect: byte-bool vs int32/float words).
// ---------------------------------------------------------------------------
__global__ void prep_mask_kernel(const unsigned char* __restrict__ m,
                                 unsigned char* __restrict__ outm) {
  __shared__ int s_ok[4];
  const int t = threadIdx.x;
  unsigned v = reinterpret_cast<const unsigned*>(m)[t];
  bool wordlike = (v <= 1u) || (v == 0x3F800000u);
  unsigned long long b = __ballot(wordlike);
  if ((t & 63) == 0) s_ok[t >> 6] = (b == ~0ull) ? 1 : 0;
  __syncthreads();
  const bool word_fmt = s_ok[0] && s_ok[1] && s_ok[2] && s_ok[3];
  for (int i = t; i < MASK_DIM * MASK_DIM; i += 256) {
    bool nz = word_fmt ? (reinterpret_cast<const unsigned*>(m)[i] != 0u)
                       : (m[i] != 0);
    outm[i] = nz ? 1 : 0;
  }
}

// ---------------------------------------------------------------------------
// x fp32 [M][K] -> bf16, pre-swizzled: 16B chunk c within each 128B span goes
// to slot c ^ (row&7).
// ---------------------------------------------------------------------------
__global__ void prep_x_swz_kernel(const float* __restrict__ x,
                                  u16* __restrict__ xb) {
  const size_t t = (size_t)blockIdx.x * 256 + threadIdx.x;  // 16B-chunk index
  const size_t row = t >> 9;        // 512 chunks per 4096-elem row
  const int wc = (int)(t & 511);
  const int blk = wc >> 3;
  const int c = wc & 7;
  const float4 v0 = *reinterpret_cast<const float4*>(x + row * K_TOT + wc * 8);
  const float4 v1 = *reinterpret_cast<const float4*>(x + row * K_TOT + wc * 8 + 4);
  s16x8 b;
  b[0] = (short)f2bf(v0.x); b[1] = (short)f2bf(v0.y);
  b[2] = (short)f2bf(v0.z); b[3] = (short)f2bf(v0.w);
  b[4] = (short)f2bf(v1.x); b[5] = (short)f2bf(v1.y);
  b[6] = (short)f2bf(v1.z); b[7] = (short)f2bf(v1.w);
  *reinterpret_cast<s16x8*>(xb + row * K_TOT + blk * 64 +
                            (size_t)((c ^ ((int)row & 7)) * 8)) = b;
}

// ---------------------------------------------------------------------------
// W fp32 [N][K] -> masked bf16, pre-swizzled (same scheme).
// ---------------------------------------------------------------------------
__global__ void prep_w_swz_kernel(const float* __restrict__ w,
                                  const unsigned char* __restrict__ mask8,
                                  u16* __restrict__ wb) {
  const size_t t = (size_t)blockIdx.x * 256 + threadIdx.x;
  const size_t row = t >> 9;
  const int wc = (int)(t & 511);
  const int blk = wc >> 3;
  const int c = wc & 7;
  s16x8 b = {};
  if (mask8[((int)row >> 5) * MASK_DIM + (wc >> 2)]) {
    const float4 v0 = *reinterpret_cast<const float4*>(w + row * K_TOT + wc * 8);
    const float4 v1 = *reinterpret_cast<const float4*>(w + row * K_TOT + wc * 8 + 4);
    b[0] = (short)f2bf(v0.x); b[1] = (short)f2bf(v0.y);
    b[2] = (short)f2bf(v0.z); b[3] = (short)f2bf(v0.w);
    b[4] = (short)f2bf(v1.x); b[5] = (short)f2bf(v1.y);
    b[6] = (short)f2bf(v1.z); b[7] = (short)f2bf(v1.w);
  }
  *reinterpret_cast<s16x8*>(wb + row * K_TOT + blk * 64 +
                            (size_t)((c ^ ((int)row & 7)) * 8)) = b;
}

// ---------------------------------------------------------------------------
// Legacy linear prep_w (for the ws-fits-W-only fallback path).
// ---------------------------------------------------------------------------
__global__ void prep_w_kernel(const float* __restrict__ w,
                              const unsigned char* __restrict__ mask8,
                              u16* __restrict__ wb) {
  const size_t e = ((size_t)blockIdx.x * blockDim.x + threadIdx.x) * 4;
  const int n = (int)(e >> 12);
  const int k = (int)(e & 4095);
  const float4 v = *reinterpret_cast<const float4*>(w + e);
  ushort4 bvec;
  if (mask8[(n >> 5) * MASK_DIM + (k >> 5)]) {
    bvec.x = f2bf(v.x); bvec.y = f2bf(v.y); bvec.z = f2bf(v.z); bvec.w = f2bf(v.w);
  } else {
    bvec.x = 0; bvec.y = 0; bvec.z = 0; bvec.w = 0;
  }
  *reinterpret_cast<ushort4*>(wb + e) = bvec;
}

// ---------------------------------------------------------------------------
// 8-phase 256x256 GEMM: C = 2 * A @ B^T + bias, A=xb, B=wb (bf16, pre-swz).
// ---------------------------------------------------------------------------
__global__ __launch_bounds__(512, 2) void gemm8_kernel(
    const u16* __restrict__ xb, const u16* __restrict__ wb,
    const float* __restrict__ bias, float* __restrict__ out) {
  extern __shared__ __align__(16) u16 lds[];  // 128 KiB: A[2][256][64], B[2][256][64]

  const int tid = threadIdx.x;
  const int lane = tid & 63;
  const int wave = tid >> 6;
  const int wr = wave >> 2;   // 0..1: rows [wr*128, +128)
  const int wc = wave & 3;    // 0..3: cols [wc*64, +64)
  const int lrow = lane & 15;
  const int g = lane >> 4;
  const int sw = (lrow & 7) << 4;  // read-side XOR (rows are 16-aligned + lrow)

  // XCD-aware bijective swizzle (grid = 1024, divisible by 8).
  int id = blockIdx.x;
  id = (id & 7) * (gridDim.x >> 3) + (id >> 3);
  const int bm = (id >> 4) << 8;  // 64 m-tiles
  const int bn = (id & 15) << 8;  // 16 n-tiles

  const int srow = tid >> 3;  // staging row 0..63 (per q-block of 64 rows)
  const int schk = tid & 7;   // staging 16B chunk

  const char* ldsb = (const char*)lds;

  f32x4 acc[8][4] = {};

  auto stage = [&](int t) {
    const int s = t & 1;
    const int k0 = t << 6;
    const u16* ga = xb + (size_t)(bm + srow) * K_TOT + k0 + schk * 8;
    const u16* gb = wb + (size_t)(bn + srow) * K_TOT + k0 + schk * 8;
    u16* la = lds + s * 16384 + wave * 512;           // wave-uniform dest base
    u16* lb = lds + 32768 + s * 16384 + wave * 512;
#pragma unroll
    for (int q = 0; q < 4; ++q) {
      load16_to_lds(ga + (size_t)(q * 64) * K_TOT, la + q * 4096);
      load16_to_lds(gb + (size_t)(q * 64) * K_TOT, lb + q * 4096);
    }
  };

  // Prologue: stage tile 0, drain, publish.
  stage(0);
  asm volatile("s_waitcnt vmcnt(0)" ::: "memory");
  __builtin_amdgcn_s_barrier();

#define PHASE(p)                                                             \
  {                                                                          \
    s16x8 af[2][2];                                                          \
    _Pragma("unroll") for (int i = 0; i < 2; ++i) {                          \
      const int ra = wr * 128 + ((p)*2 + i) * 16 + lrow;                     \
      const char* rp = ldsb + abase + ra * 128;                              \
      _Pragma("unroll") for (int ks = 0; ks < 2; ++ks)                       \
        af[i][ks] = *reinterpret_cast<const s16x8*>(                         \
            rp + ((ks * 64 + g * 16) ^ sw));                                 \
    }                                                                        \
    __builtin_amdgcn_s_barrier();                                            \
    asm volatile("s_waitcnt lgkmcnt(0)" ::: "memory");                       \
    __builtin_amdgcn_sched_barrier(0);                                       \
    __builtin_amdgcn_s_setprio(1);                                           \
    _Pragma("unroll") for (int i = 0; i < 2; ++i)                            \
      _Pragma("unroll") for (int n = 0; n < 4; ++n)                          \
        _Pragma("unroll") for (int ks = 0; ks < 2; ++ks)                     \
          acc[(p)*2 + i][n] = __builtin_amdgcn_mfma_f32_16x16x32_bf16(       \
              af[i][ks], bf[n][ks], acc[(p)*2 + i][n], 0, 0, 0);             \
    __builtin_amdgcn_s_setprio(0);                                           \
  }

  for (int t = 0; t < K_TOT / 64; ++t) {
    const int s = t & 1;
    const int abase = s * 32768;          // bytes
    const int bbase = 65536 + s * 32768;  // bytes

    // Phase 0 front: issue next tile's staging (slot s^1 is free: tile t-1's
    // reads all retired at its last lgkmcnt(0) before the closing barrier).
    if (t < K_TOT / 64 - 1) stage(t + 1);

    // B fragments for the whole tile (held in registers across phases).
    s16x8 bf[4][2];
#pragma unroll
    for (int n = 0; n < 4; ++n) {
      const int rb = wc * 64 + n * 16 + lrow;
      const char* rp = ldsb + bbase + rb * 128;
#pragma unroll
      for (int ks = 0; ks < 2; ++ks)
        bf[n][ks] = *reinterpret_cast<const s16x8*>(
            rp + ((ks * 64 + g * 16) ^ sw));
    }

    PHASE(0);
    __builtin_amdgcn_s_barrier();
    PHASE(1);
    __builtin_amdgcn_s_barrier();
    PHASE(2);
    __builtin_amdgcn_s_barrier();
    PHASE(3);
    // Drain next tile's stages (issued ~3 phases ago) and publish slot s^1.
    asm volatile("s_waitcnt vmcnt(0)" ::: "memory");
    __builtin_amdgcn_s_barrier();
  }
#undef PHASE

  // Epilogue: out = 2*acc + bias. C/D frag: col = lane&15, row = g*4 + j.
#pragma unroll
  for (int n = 0; n < 4; ++n) {
    const int gcol = bn + wc * 64 + n * 16 + lrow;
    const float bv = bias[gcol];
#pragma unroll
    for (int m = 0; m < 8; ++m) {
      const int grow = bm + wr * 128 + m * 16 + (g << 2);
#pragma unroll
      for (int j = 0; j < 4; ++j)
        out[(size_t)(grow + j) * N_TOT + gcol] = 2.0f * acc[m][n][j] + bv;
    }
  }
}

// ---------------------------------------------------------------------------
// Legacy reg-staged GEMM (fallback when ws can't hold xb).
// ---------------------------------------------------------------------------
template <bool PREPPED>
__global__ __launch_bounds__(256) void gemm_kernel(
    const float* __restrict__ x, const u16* __restrict__ wb,
    const float* __restrict__ wf, const unsigned char* __restrict__ mask8,
    const float* __restrict__ bias, float* __restrict__ out) {
  __shared__ __align__(16) u16 As[128 * LDS_STRIDE];
  __shared__ __align__(16) u16 Bs[128 * LDS_STRIDE];

  const int tid = threadIdx.x;
  const int lane = tid & 63;
  const int wave = tid >> 6;
  const int wr = wave >> 1;
  const int wcn = wave & 1;

  int id = blockIdx.x;
  const int cpx = gridDim.x >> 3;
  id = (id & 7) * cpx + (id >> 3);
  const int bm = (id >> 5) << 7;
  const int bn = (id & 31) << 7;

  const int arow = tid >> 4;
  const int acol = (tid & 15) << 2;
  const int brow = tid >> 3;
  const int bcol = (tid & 7) << 3;

  const int lrow = lane & 15;
  const int lgo = (lane >> 4) << 3;

  f32x4 acc[4][4] = {};

  for (int k0 = 0; k0 < K_TOT; k0 += 64) {
#pragma unroll
    for (int r = 0; r < 8; ++r) {
      const int row = arow + r * 16;
      const float4 v = *reinterpret_cast<const float4*>(
          x + (size_t)(bm + row) * K_TOT + k0 + acol);
      ushort4 bvec;
      bvec.x = f2bf(v.x); bvec.y = f2bf(v.y); bvec.z = f2bf(v.z); bvec.w = f2bf(v.w);
      *reinterpret_cast<ushort4*>(&As[row * LDS_STRIDE + acol]) = bvec;
    }
    if (PREPPED) {
#pragma unroll
      for (int r = 0; r < 4; ++r) {
        const int row = brow + r * 32;
        const s16x8 v = *reinterpret_cast<const s16x8*>(
            wb + (size_t)(bn + row) * K_TOT + k0 + bcol);
        *reinterpret_cast<s16x8*>(&Bs[row * LDS_STRIDE + bcol]) = v;
      }
    } else {
#pragma unroll
      for (int r = 0; r < 8; ++r) {
        const int row = arow + r * 16;
        const float4 v = *reinterpret_cast<const float4*>(
            wf + (size_t)(bn + row) * K_TOT + k0 + acol);
        ushort4 bvec;
        bvec.x = 0; bvec.y = 0; bvec.z = 0; bvec.w = 0;
        if (mask8[((bn + row) >> 5) * MASK_DIM + ((k0 + acol) >> 5)]) {
          bvec.x = f2bf(v.x); bvec.y = f2bf(v.y); bvec.z = f2bf(v.z); bvec.w = f2bf(v.w);
        }
        *reinterpret_cast<ushort4*>(&Bs[row * LDS_STRIDE + acol]) = bvec;
      }
    }
    __syncthreads();

#pragma unroll
    for (int ks = 0; ks < 2; ++ks) {
      s16x8 af[4], bfv[4];
#pragma unroll
      for (int m = 0; m < 4; ++m)
        af[m] = *reinterpret_cast<const s16x8*>(
            &As[(wr * 64 + m * 16 + lrow) * LDS_STRIDE + ks * 32 + lgo]);
#pragma unroll
      for (int n = 0; n < 4; ++n)
        bfv[n] = *reinterpret_cast<const s16x8*>(
            &Bs[(wcn * 64 + n * 16 + lrow) * LDS_STRIDE + ks * 32 + lgo]);
#pragma unroll
      for (int m = 0; m < 4; ++m)
#pragma unroll
        for (int n = 0; n < 4; ++n)
          acc[m][n] = __builtin_amdgcn_mfma_f32_16x16x32_bf16(af[m], bfv[n],
                                                              acc[m][n], 0, 0, 0);
    }
    __syncthreads();
  }

#pragma unroll
  for (int n = 0; n < 4; ++n) {
    const int gcol = bn + wcn * 64 + n * 16 + lrow;
    const float bv = bias[gcol];
#pragma unroll
    for (int m = 0; m < 4; ++m) {
      const int grow = bm + wr * 64 + m * 16 + ((lane >> 4) << 2);
#pragma unroll
      for (int j = 0; j < 4; ++j) {
        out[(size_t)(grow + j) * N_TOT + gcol] = 2.0f * acc[m][n][j] + bv;
      }
    }
  }
}

extern "C" void kernel_launch(void* const* d_in, const int* in_sizes, int n_in,
                              void* d_out, int out_size, void* d_ws, size_t ws_size,
                              hipStream_t stream) {
  const float* x = (const float*)d_in[0];
  const float* w = (const float*)d_in[1];
  const float* bias = (const float*)d_in[2];
  const unsigned char* mask_raw = (const unsigned char*)d_in[3];
  float* out = (float*)d_out;

  unsigned char* ws_mask = (unsigned char*)d_ws;            // 16 KiB (64 KiB slot)
  u16* wb = (u16*)((char*)d_ws + 65536);                    // 32 MiB bf16 W
  u16* xb = (u16*)((char*)d_ws + 65536 +
                   (size_t)N_TOT * K_TOT * sizeof(u16));    // 128 MiB bf16 x
  const size_t need_w = 65536 + (size_t)N_TOT * K_TOT * sizeof(u16);
  const size_t need_full = need_w + (size_t)M_TOT * K_TOT * sizeof(u16);

  prep_mask_kernel<<<1, 256, 0, stream>>>(mask_raw, ws_mask);

  if (ws_size >= need_full) {
    prep_w_swz_kernel<<<(N_TOT * (K_TOT / 8)) / 256, 256, 0, stream>>>(w, ws_mask, wb);
    prep_x_swz_kernel<<<(M_TOT * (K_TOT / 8)) / 256, 256, 0, stream>>>(x, xb);
    hipFuncSetAttribute(reinterpret_cast<const void*>(gemm8_kernel),
                        hipFuncAttributeMaxDynamicSharedMemorySize, 131072);
    gemm8_kernel<<<(M_TOT / 256) * (N_TOT / 256), 512, 131072, stream>>>(
        xb, wb, bias, out);
  } else if (ws_size >= need_w) {
    prep_w_kernel<<<(N_TOT * K_TOT) / (256 * 4), 256, 0, stream>>>(w, ws_mask, wb);
    gemm_kernel<true><<<(M_TOT / 128) * (N_TOT / 128), 256, 0, stream>>>(
        x, wb, nullptr, nullptr, bias, out);
  } else {
    gemm_kernel<false><<<(M_TOT / 128) * (N_TOT / 128), 256, 0, stream>>>(
        x, nullptr, w, ws_mask, bias, out);
  }
}

// Round 4
// 598.382 us; speedup vs baseline: 2.1528x; 1.1480x over previous
//
#include <hip/hip_runtime.h>

// BlockSparseLinear: out[M,N] = 2 * (x[M,K] @ (W .* mask)^T) + bias[N]
// M = 16384, N = 4096, K = 4096, mask 32x32 blocks over (128,128).
// Fast path: prep x and masked W to bf16 in d_ws, PRE-SWIZZLED (16B chunk
// c -> c ^ ((row>>1)&3) within each 64B span == BK=32 K-tile row);
// GEMM: 256x256 tile, BK=32, 8 waves (2Mx4N), 4-slot LDS ring (128 KiB),
// prefetch depth 3, counted vmcnt(8) (never drain-0 in main loop),
// per-phase barrier/lgkmcnt/setprio MFMA clusters, SGPR bit-mask sparsity
// skip (~50% of MFMA clusters), XCD-aware block swizzle.

typedef short s16x8 __attribute__((ext_vector_type(8)));
typedef float f32x4 __attribute__((ext_vector_type(4)));
typedef unsigned short u16;

#define M_TOT 16384
#define N_TOT 4096
#define K_TOT 4096
#define MASK_DIM 128
#define LDS_STRIDE 72  // legacy fallback kernel only

__device__ __forceinline__ u16 f2bf(float f) {
  union { float f; unsigned u; } v; v.f = f;
  unsigned r = v.u + 0x7FFFu + ((v.u >> 16) & 1u);  // round-to-nearest-even
  return (u16)(r >> 16);
}

__device__ __forceinline__ void load16_to_lds(const u16* g, u16* l) {
  __builtin_amdgcn_global_load_lds(
      (const __attribute__((address_space(1))) void*)g,
      (__attribute__((address_space(3))) void*)l, 16, 0, 0);
}

// ---------------------------------------------------------------------------
// Mask normalization (format auto-detect) + bit-pack (maskbits[row][4] u32).
// Single block.
// ---------------------------------------------------------------------------
__global__ void prep_mask_kernel(const unsigned char* __restrict__ m,
                                 unsigned char* __restrict__ outm,
                                 unsigned* __restrict__ outbits) {
  __shared__ int s_ok[4];
  const int t = threadIdx.x;
  unsigned v = reinterpret_cast<const unsigned*>(m)[t];
  bool wordlike = (v <= 1u) || (v == 0x3F800000u);
  unsigned long long b = __ballot(wordlike);
  if ((t & 63) == 0) s_ok[t >> 6] = (b == ~0ull) ? 1 : 0;
  __syncthreads();
  const bool word_fmt = s_ok[0] && s_ok[1] && s_ok[2] && s_ok[3];
  for (int i = t; i < MASK_DIM * MASK_DIM; i += 256) {
    bool nz = word_fmt ? (reinterpret_cast<const unsigned*>(m)[i] != 0u)
                       : (m[i] != 0);
    outm[i] = nz ? 1 : 0;
  }
  __syncthreads();
  // bit-pack: 512 words total (128 rows x 4); word w of row r covers cols
  // w*32..w*32+31.
  for (int i = t; i < MASK_DIM * 4; i += 256) {
    const int r = i >> 2, w = i & 3;
    unsigned acc = 0;
    for (int bit = 0; bit < 32; ++bit)
      acc |= (unsigned)(outm[r * MASK_DIM + w * 32 + bit] != 0) << bit;
    outbits[i] = acc;
  }
}

// ---------------------------------------------------------------------------
// x fp32 [M][K] -> bf16, pre-swizzled: within each 32-elem K-tile (64B), 16B
// chunk c goes to slot c ^ ((row>>1)&3).
// ---------------------------------------------------------------------------
__global__ void prep_x_swz_kernel(const float* __restrict__ x,
                                  u16* __restrict__ xb) {
  const size_t t = (size_t)blockIdx.x * 256 + threadIdx.x;  // 16B-chunk index
  const size_t row = t >> 9;        // 512 chunks per 4096-elem row
  const int wc = (int)(t & 511);
  const int blk = wc >> 2;          // K-tile 0..127
  const int c = wc & 3;             // chunk within tile
  const float4 v0 = *reinterpret_cast<const float4*>(x + row * K_TOT + wc * 8);
  const float4 v1 = *reinterpret_cast<const float4*>(x + row * K_TOT + wc * 8 + 4);
  s16x8 b;
  b[0] = (short)f2bf(v0.x); b[1] = (short)f2bf(v0.y);
  b[2] = (short)f2bf(v0.z); b[3] = (short)f2bf(v0.w);
  b[4] = (short)f2bf(v1.x); b[5] = (short)f2bf(v1.y);
  b[6] = (short)f2bf(v1.z); b[7] = (short)f2bf(v1.w);
  *reinterpret_cast<s16x8*>(xb + row * K_TOT + blk * 32 +
                            (size_t)((c ^ (((int)row >> 1) & 3)) * 8)) = b;
}

// ---------------------------------------------------------------------------
// W fp32 [N][K] -> masked bf16, pre-swizzled (same scheme).
// ---------------------------------------------------------------------------
__global__ void prep_w_swz_kernel(const float* __restrict__ w,
                                  const unsigned char* __restrict__ mask8,
                                  u16* __restrict__ wb) {
  const size_t t = (size_t)blockIdx.x * 256 + threadIdx.x;
  const size_t row = t >> 9;
  const int wc = (int)(t & 511);
  const int blk = wc >> 2;
  const int c = wc & 3;
  s16x8 b = {};
  if (mask8[((int)row >> 5) * MASK_DIM + blk]) {
    const float4 v0 = *reinterpret_cast<const float4*>(w + row * K_TOT + wc * 8);
    const float4 v1 = *reinterpret_cast<const float4*>(w + row * K_TOT + wc * 8 + 4);
    b[0] = (short)f2bf(v0.x); b[1] = (short)f2bf(v0.y);
    b[2] = (short)f2bf(v0.z); b[3] = (short)f2bf(v0.w);
    b[4] = (short)f2bf(v1.x); b[5] = (short)f2bf(v1.y);
    b[6] = (short)f2bf(v1.z); b[7] = (short)f2bf(v1.w);
  }
  *reinterpret_cast<s16x8*>(wb + row * K_TOT + blk * 32 +
                            (size_t)((c ^ (((int)row >> 1) & 3)) * 8)) = b;
}

// ---------------------------------------------------------------------------
// Legacy linear prep_w (for the ws-fits-W-only fallback path).
// ---------------------------------------------------------------------------
__global__ void prep_w_kernel(const float* __restrict__ w,
                              const unsigned char* __restrict__ mask8,
                              u16* __restrict__ wb) {
  const size_t e = ((size_t)blockIdx.x * blockDim.x + threadIdx.x) * 4;
  const int n = (int)(e >> 12);
  const int k = (int)(e & 4095);
  const float4 v = *reinterpret_cast<const float4*>(w + e);
  ushort4 bvec;
  if (mask8[(n >> 5) * MASK_DIM + (k >> 5)]) {
    bvec.x = f2bf(v.x); bvec.y = f2bf(v.y); bvec.z = f2bf(v.z); bvec.w = f2bf(v.w);
  } else {
    bvec.x = 0; bvec.y = 0; bvec.z = 0; bvec.w = 0;
  }
  *reinterpret_cast<ushort4*>(wb + e) = bvec;
}

// ---------------------------------------------------------------------------
// Deep-pipeline 256x256 GEMM, BK=32, 4-slot LDS ring, counted vmcnt,
// SGPR-bitmask sparsity skip.  C = 2 * A @ B^T + bias.
// ---------------------------------------------------------------------------
__global__ __launch_bounds__(512, 2) void gemm8_kernel(
    const u16* __restrict__ xb, const u16* __restrict__ wb,
    const unsigned* __restrict__ maskbits,
    const float* __restrict__ bias, float* __restrict__ out) {
  extern __shared__ __align__(16) u16 lds[];  // A[4][256][32] | B[4][256][32]

  const int tid = threadIdx.x;
  const int lane = tid & 63;
  const int wave = tid >> 6;
  const int wr = wave >> 2;   // 0..1: rows [wr*128, +128)
  const int wc = wave & 3;    // 0..3: cols [wc*64, +64)
  const int lrow = lane & 15;
  const int g = lane >> 4;
  const int kphys = ((g ^ ((lrow >> 1) & 3)) << 4);  // physical 16B chunk byte

  // XCD-aware bijective swizzle (grid = 1024, divisible by 8).
  int id = blockIdx.x;
  id = (id & 7) * (gridDim.x >> 3) + (id >> 3);
  const int bm = (id >> 4) << 8;  // 64 m-tiles
  const int bn = (id & 15) << 8;  // 16 n-tiles

  const char* ldsb = (const char*)lds;

  // Wave-uniform sparsity bits: mask rows for n-pair 0 (cols wc*64..+31) and
  // n-pair 1 (cols wc*64+32..+63), 128 bits each as 2x u64 in SGPRs.
  {}
  const unsigned* mb = maskbits + (((bn + wc * 64) >> 5) << 2);
  const unsigned w0 = __builtin_amdgcn_readfirstlane(mb[0]);
  const unsigned w1 = __builtin_amdgcn_readfirstlane(mb[1]);
  const unsigned w2 = __builtin_amdgcn_readfirstlane(mb[2]);
  const unsigned w3 = __builtin_amdgcn_readfirstlane(mb[3]);
  const unsigned w4 = __builtin_amdgcn_readfirstlane(mb[4]);
  const unsigned w5 = __builtin_amdgcn_readfirstlane(mb[5]);
  const unsigned w6 = __builtin_amdgcn_readfirstlane(mb[6]);
  const unsigned w7 = __builtin_amdgcn_readfirstlane(mb[7]);
  const unsigned long long m0lo = (unsigned long long)w0 | ((unsigned long long)w1 << 32);
  const unsigned long long m0hi = (unsigned long long)w2 | ((unsigned long long)w3 << 32);
  const unsigned long long m1lo = (unsigned long long)w4 | ((unsigned long long)w5 << 32);
  const unsigned long long m1hi = (unsigned long long)w6 | ((unsigned long long)w7 << 32);

  f32x4 acc[8][4] = {};

  auto stage = [&](int t) {
    const int s = t & 3;
    const int k0 = t << 5;
    const u16* ga = xb + (size_t)(bm + (tid >> 2)) * K_TOT + k0 + (tid & 3) * 8;
    const u16* gb = wb + (size_t)(bn + (tid >> 2)) * K_TOT + k0 + (tid & 3) * 8;
    u16* la = lds + s * 8192 + wave * 512;            // wave-uniform dest base
    u16* lb = lds + 32768 + s * 8192 + wave * 512;
    load16_to_lds(ga, la);
    load16_to_lds(ga + (size_t)128 * K_TOT, la + 4096);
    load16_to_lds(gb, lb);
    load16_to_lds(gb + (size_t)128 * K_TOT, lb + 4096);
  };

  // Prologue: fill pipeline 3 deep (12 loads in flight).
  stage(0);
  stage(1);
  stage(2);

#define TILE(t, VMSTR)                                                        \
  {                                                                           \
    const int s = (t) & 3;                                                    \
    const int abase = s * 16384;                                              \
    const int bbase = 65536 + s * 16384;                                      \
    asm volatile("s_waitcnt " VMSTR ::: "memory");                            \
    __builtin_amdgcn_s_barrier();                                             \
    if ((t) <= (K_TOT / 32) - 4) stage((t) + 3);                              \
    const unsigned long long sel0 = ((t) & 64) ? m0hi : m0lo;                 \
    const unsigned long long sel1 = ((t) & 64) ? m1hi : m1lo;                 \
    const int sh = (t) & 63;                                                  \
    const int b0 = (int)((sel0 >> sh) & 1);                                   \
    const int b1 = (int)((sel1 >> sh) & 1);                                   \
    s16x8 bfv[4];                                                             \
    if (b0) {                                                                 \
      bfv[0] = *reinterpret_cast<const s16x8*>(                               \
          ldsb + bbase + (wc * 64 + 0 * 16 + lrow) * 64 + kphys);             \
      bfv[1] = *reinterpret_cast<const s16x8*>(                               \
          ldsb + bbase + (wc * 64 + 1 * 16 + lrow) * 64 + kphys);             \
    }                                                                         \
    if (b1) {                                                                 \
      bfv[2] = *reinterpret_cast<const s16x8*>(                               \
          ldsb + bbase + (wc * 64 + 2 * 16 + lrow) * 64 + kphys);             \
      bfv[3] = *reinterpret_cast<const s16x8*>(                               \
          ldsb + bbase + (wc * 64 + 3 * 16 + lrow) * 64 + kphys);             \
    }                                                                         \
    if (b0 | b1) {                                                            \
      s16x8 af[4];                                                            \
      _Pragma("unroll") for (int m = 0; m < 4; ++m)                           \
          af[m] = *reinterpret_cast<const s16x8*>(                            \
              ldsb + abase + (wr * 128 + m * 16 + lrow) * 64 + kphys);        \
      asm volatile("s_waitcnt lgkmcnt(0)" ::: "memory");                      \
      __builtin_amdgcn_sched_barrier(0);                                      \
      __builtin_amdgcn_s_setprio(1);                                          \
      if (b0) {                                                               \
        _Pragma("unroll") for (int m = 0; m < 4; ++m)                         \
            _Pragma("unroll") for (int n = 0; n < 2; ++n)                     \
                acc[m][n] = __builtin_amdgcn_mfma_f32_16x16x32_bf16(          \
                    af[m], bfv[n], acc[m][n], 0, 0, 0);                       \
      }                                                                       \
      if (b1) {                                                               \
        _Pragma("unroll") for (int m = 0; m < 4; ++m)                         \
            _Pragma("unroll") for (int n = 2; n < 4; ++n)                     \
                acc[m][n] = __builtin_amdgcn_mfma_f32_16x16x32_bf16(          \
                    af[m], bfv[n], acc[m][n], 0, 0, 0);                       \
      }                                                                       \
      __builtin_amdgcn_s_setprio(0);                                          \
    }                                                                         \
    __builtin_amdgcn_s_barrier();                                             \
    if (b0 | b1) {                                                            \
      s16x8 af[4];                                                            \
      _Pragma("unroll") for (int m = 0; m < 4; ++m)                           \
          af[m] = *reinterpret_cast<const s16x8*>(                            \
              ldsb + abase + (wr * 128 + (m + 4) * 16 + lrow) * 64 + kphys);  \
      asm volatile("s_waitcnt lgkmcnt(0)" ::: "memory");                      \
      __builtin_amdgcn_sched_barrier(0);                                      \
      __builtin_amdgcn_s_setprio(1);                                          \
      if (b0) {                                                               \
        _Pragma("unroll") for (int m = 0; m < 4; ++m)                         \
            _Pragma("unroll") for (int n = 0; n < 2; ++n)                     \
                acc[m + 4][n] = __builtin_amdgcn_mfma_f32_16x16x32_bf16(      \
                    af[m], bfv[n], acc[m + 4][n], 0, 0, 0);                   \
      }                                                                       \
      if (b1) {                                                               \
        _Pragma("unroll") for (int m = 0; m < 4; ++m)                         \
            _Pragma("unroll") for (int n = 2; n < 4; ++n)                     \
                acc[m + 4][n] = __builtin_amdgcn_mfma_f32_16x16x32_bf16(      \
                    af[m], bfv[n], acc[m + 4][n], 0, 0, 0);                   \
      }                                                                       \
      __builtin_amdgcn_s_setprio(0);                                          \
    }                                                                         \
  }

  for (int t = 0; t < K_TOT / 32 - 2; ++t) TILE(t, "vmcnt(8)");
  TILE(K_TOT / 32 - 2, "vmcnt(4)");
  TILE(K_TOT / 32 - 1, "vmcnt(0)");
#undef TILE

  // Epilogue: out = 2*acc + bias. C/D frag: col = lane&15, row = g*4 + j.
#pragma unroll
  for (int n = 0; n < 4; ++n) {
    const int gcol = bn + wc * 64 + n * 16 + lrow;
    const float bv = bias[gcol];
#pragma unroll
    for (int m = 0; m < 8; ++m) {
      const int grow = bm + wr * 128 + m * 16 + (g << 2);
#pragma unroll
      for (int j = 0; j < 4; ++j)
        out[(size_t)(grow + j) * N_TOT + gcol] = 2.0f * acc[m][n][j] + bv;
    }
  }
}

// ---------------------------------------------------------------------------
// Legacy reg-staged GEMM (fallback when ws can't hold xb).
// ---------------------------------------------------------------------------
template <bool PREPPED>
__global__ __launch_bounds__(256) void gemm_kernel(
    const float* __restrict__ x, const u16* __restrict__ wb,
    const float* __restrict__ wf, const unsigned char* __restrict__ mask8,
    const float* __restrict__ bias, float* __restrict__ out) {
  __shared__ __align__(16) u16 As[128 * LDS_STRIDE];
  __shared__ __align__(16) u16 Bs[128 * LDS_STRIDE];

  const int tid = threadIdx.x;
  const int lane = tid & 63;
  const int wave = tid >> 6;
  const int wr = wave >> 1;
  const int wcn = wave & 1;

  int id = blockIdx.x;
  const int cpx = gridDim.x >> 3;
  id = (id & 7) * cpx + (id >> 3);
  const int bm = (id >> 5) << 7;
  const int bn = (id & 31) << 7;

  const int arow = tid >> 4;
  const int acol = (tid & 15) << 2;
  const int brow = tid >> 3;
  const int bcol = (tid & 7) << 3;

  const int lrow = lane & 15;
  const int lgo = (lane >> 4) << 3;

  f32x4 acc[4][4] = {};

  for (int k0 = 0; k0 < K_TOT; k0 += 64) {
#pragma unroll
    for (int r = 0; r < 8; ++r) {
      const int row = arow + r * 16;
      const float4 v = *reinterpret_cast<const float4*>(
          x + (size_t)(bm + row) * K_TOT + k0 + acol);
      ushort4 bvec;
      bvec.x = f2bf(v.x); bvec.y = f2bf(v.y); bvec.z = f2bf(v.z); bvec.w = f2bf(v.w);
      *reinterpret_cast<ushort4*>(&As[row * LDS_STRIDE + acol]) = bvec;
    }
    if (PREPPED) {
#pragma unroll
      for (int r = 0; r < 4; ++r) {
        const int row = brow + r * 32;
        const s16x8 v = *reinterpret_cast<const s16x8*>(
            wb + (size_t)(bn + row) * K_TOT + k0 + bcol);
        *reinterpret_cast<s16x8*>(&Bs[row * LDS_STRIDE + bcol]) = v;
      }
    } else {
#pragma unroll
      for (int r = 0; r < 8; ++r) {
        const int row = arow + r * 16;
        const float4 v = *reinterpret_cast<const float4*>(
            wf + (size_t)(bn + row) * K_TOT + k0 + acol);
        ushort4 bvec;
        bvec.x = 0; bvec.y = 0; bvec.z = 0; bvec.w = 0;
        if (mask8[((bn + row) >> 5) * MASK_DIM + ((k0 + acol) >> 5)]) {
          bvec.x = f2bf(v.x); bvec.y = f2bf(v.y); bvec.z = f2bf(v.z); bvec.w = f2bf(v.w);
        }
        *reinterpret_cast<ushort4*>(&Bs[row * LDS_STRIDE + acol]) = bvec;
      }
    }
    __syncthreads();

#pragma unroll
    for (int ks = 0; ks < 2; ++ks) {
      s16x8 af[4], bfv[4];
#pragma unroll
      for (int m = 0; m < 4; ++m)
        af[m] = *reinterpret_cast<const s16x8*>(
            &As[(wr * 64 + m * 16 + lrow) * LDS_STRIDE + ks * 32 + lgo]);
#pragma unroll
      for (int n = 0; n < 4; ++n)
        bfv[n] = *reinterpret_cast<const s16x8*>(
            &Bs[(wcn * 64 + n * 16 + lrow) * LDS_STRIDE + ks * 32 + lgo]);
#pragma unroll
      for (int m = 0; m < 4; ++m)
#pragma unroll
        for (int n = 0; n < 4; ++n)
          acc[m][n] = __builtin_amdgcn_mfma_f32_16x16x32_bf16(af[m], bfv[n],
                                                              acc[m][n], 0, 0, 0);
    }
    __syncthreads();
  }

#pragma unroll
  for (int n = 0; n < 4; ++n) {
    const int gcol = bn + wcn * 64 + n * 16 + lrow;
    const float bv = bias[gcol];
#pragma unroll
    for (int m = 0; m < 4; ++m) {
      const int grow = bm + wr * 64 + m * 16 + ((lane >> 4) << 2);
#pragma unroll
      for (int j = 0; j < 4; ++j) {
        out[(size_t)(grow + j) * N_TOT + gcol] = 2.0f * acc[m][n][j] + bv;
      }
    }
  }
}

extern "C" void kernel_launch(void* const* d_in, const int* in_sizes, int n_in,
                              void* d_out, int out_size, void* d_ws, size_t ws_size,
                              hipStream_t stream) {
  const float* x = (const float*)d_in[0];
  const float* w = (const float*)d_in[1];
  const float* bias = (const float*)d_in[2];
  const unsigned char* mask_raw = (const unsigned char*)d_in[3];
  float* out = (float*)d_out;

  unsigned char* ws_mask = (unsigned char*)d_ws;            // 16 KiB mask8
  unsigned* ws_bits = (unsigned*)((char*)d_ws + 16384);     // 2 KiB bitmask
  u16* wb = (u16*)((char*)d_ws + 65536);                    // 32 MiB bf16 W
  u16* xb = (u16*)((char*)d_ws + 65536 +
                   (size_t)N_TOT * K_TOT * sizeof(u16));    // 128 MiB bf16 x
  const size_t need_w = 65536 + (size_t)N_TOT * K_TOT * sizeof(u16);
  const size_t need_full = need_w + (size_t)M_TOT * K_TOT * sizeof(u16);

  prep_mask_kernel<<<1, 256, 0, stream>>>(mask_raw, ws_mask, ws_bits);

  if (ws_size >= need_full) {
    prep_w_swz_kernel<<<(N_TOT * (K_TOT / 8)) / 256, 256, 0, stream>>>(w, ws_mask, wb);
    prep_x_swz_kernel<<<(M_TOT * (K_TOT / 8)) / 256, 256, 0, stream>>>(x, xb);
    hipFuncSetAttribute(reinterpret_cast<const void*>(gemm8_kernel),
                        hipFuncAttributeMaxDynamicSharedMemorySize, 131072);
    gemm8_kernel<<<(M_TOT / 256) * (N_TOT / 256), 512, 131072, stream>>>(
        xb, wb, ws_bits, bias, out);
  } else if (ws_size >= need_w) {
    prep_w_kernel<<<(N_TOT * K_TOT) / (256 * 4), 256, 0, stream>>>(w, ws_mask, wb);
    gemm_kernel<true><<<(M_TOT / 128) * (N_TOT / 128), 256, 0, stream>>>(
        x, wb, nullptr, nullptr, bias, out);
  } else {
    gemm_kernel<false><<<(M_TOT / 128) * (N_TOT / 128), 256, 0, stream>>>(
        x, nullptr, w, ws_mask, bias, out);
  }
}